// Round 18
// baseline (391.751 us; speedup 1.0000x reference)
//
#include <hip/hip_runtime.h>
#include <stdint.h>

typedef float f32x4 __attribute__((ext_vector_type(4)));
typedef short s16x8 __attribute__((ext_vector_type(8)));
typedef unsigned u32x4 __attribute__((ext_vector_type(4)));

#define B_SZ 256
#define A_RG 196
#define DVD  2048
#define RNN  1024
#define H_SZ 512
#define NKT  (DVD / 32)       // 64 K-tiles

__device__ __forceinline__ unsigned short f2bf(float f) {
    unsigned u = __builtin_bit_cast(unsigned, f);
    u = u + 0x7FFFu + ((u >> 16) & 1u);   // RNE
    return (unsigned short)(u >> 16);
}

__device__ __forceinline__ unsigned cvt2(float a, float b) {
    unsigned r;
    asm("v_cvt_pk_bf16_f32 %0, %1, %2" : "=v"(r) : "v"(a), "v"(b));
    return r;
}

__device__ __forceinline__ void gll16(const void* g, void* l) {
    __builtin_amdgcn_global_load_lds(
        (const __attribute__((address_space(1))) void*)g,
        (__attribute__((address_space(3))) void*)l, 16, 0, 0);
}

// ---------------------------------------------------------------------------
// Kernel 1: W_v [2048,512] fp32 -> Wt4 bf16 in MFMA-B-fragment order
// (R11/R13-verified): ushort idx = ((kt*32 + f)*64 + g*16 + lr)*8 + e,
// f=col>>4, lr=col&15, kt=k>>5, g=(k>>3)&3, e=k&7. Tile kt = contiguous
// 32 KB; linear gll copy -> frag f at LDS slab f*1024 + lane*16
// (contiguous ds_read_b128, conflict-free).
// ---------------------------------------------------------------------------
__global__ __launch_bounds__(256) void k_prepW(const float* __restrict__ Wv,
                                               unsigned short* __restrict__ Wt4) {
    __shared__ float tile[64][65];
    int kb = blockIdx.x >> 3, ct = blockIdx.x & 7;
    int k0 = kb * 64, c0 = ct * 64;
    int t = threadIdx.x;
    int cl = t & 63, rq = t >> 6;
#pragma unroll
    for (int i = 0; i < 16; ++i) {
        int r = rq * 16 + i;
        tile[r][cl] = Wv[(size_t)(k0 + r) * H_SZ + c0 + cl];
    }
    __syncthreads();
    int kl = t & 63;
#pragma unroll
    for (int i = 0; i < 16; ++i) {
        int cr = rq * 16 + i;
        int col = c0 + cr;
        int k = k0 + kl;
        int f = col >> 4, lr = col & 15;
        int kt = k >> 5, g = (k >> 3) & 3, e = k & 7;
        size_t dst = ((size_t)(kt * 32 + f) * 64 + g * 16 + lr) * 8 + e;
        Wt4[dst] = f2bf(tile[kl][cr]);
    }
}

// ---------------------------------------------------------------------------
// Kernel 2: base[b,h] = h_att[b]@W_ha + prev_h2[b]@W_hv + b_ha + b_hv + b_v
// ---------------------------------------------------------------------------
__global__ __launch_bounds__(256) void k_base(const float* __restrict__ h_att,
                                              const float* __restrict__ prev_h2,
                                              const float* __restrict__ W_ha,
                                              const float* __restrict__ b_ha,
                                              const float* __restrict__ W_hv,
                                              const float* __restrict__ b_hv,
                                              const float* __restrict__ b_v,
                                              float* __restrict__ base_g) {
    __shared__ float ha_s[4][RNN];
    __shared__ float pv_s[4][RNN];
    int bg = blockIdx.x >> 2, hg = blockIdx.x & 3;
    int t = threadIdx.x;
#pragma unroll
    for (int i = 0; i < 16; ++i) {
        int idx = i * 256 + t;
        int bl = idx >> 10, k = idx & 1023;
        ha_s[bl][k] = h_att[(size_t)(bg * 4 + bl) * RNN + k];
        pv_s[bl][k] = prev_h2[(size_t)(bg * 4 + bl) * RNN + k];
    }
    __syncthreads();
    int h = hg * 128 + (t & 127);
    int br = t >> 7;
    float aA0 = 0, aA1 = 0, aV0 = 0, aV1 = 0;
#pragma unroll 4
    for (int k = 0; k < RNN; ++k) {
        float w1 = W_ha[(size_t)k * H_SZ + h];
        float w2 = W_hv[(size_t)k * H_SZ + h];
        aA0 = fmaf(ha_s[br * 2][k],     w1, aA0);
        aA1 = fmaf(ha_s[br * 2 + 1][k], w1, aA1);
        aV0 = fmaf(pv_s[br * 2][k],     w2, aV0);
        aV1 = fmaf(pv_s[br * 2 + 1][k], w2, aV1);
    }
    float bias = b_ha[h] + b_hv[h] + b_v[h];
    base_g[(size_t)(bg * 4 + br * 2) * H_SZ + h]     = aA0 + aV0 + bias;
    base_g[(size_t)(bg * 4 + br * 2 + 1) * H_SZ + h] = aA1 + aV1 + bias;
}

// ---------------------------------------------------------------------------
// Kernel 3 (fused, R18): ALL operands staged via global_load_lds -> zero
// register-vmem in the K loop -> every vmcnt is a counted wait with a
// >=1-kstep window (A: 2 ksteps >= 900cy HBM; B: 1 kstep >= 300cy L2).
// A kept fp32 in LDS (4 x 16KB ring, 128B rows span all 32 banks; source
// pre-swizzled (l&7)^(l>>3), reads 2-way-free), cvt_pk at fragment read.
// B bf16 fragment-packed (2 x 32KB dbuf, linear, conflict-free).
// 1024 thr = 16 waves (2M x 8N), wave 64x64, acc[4][4]=64 AGPR.
// Score -> online softmax -> V accumulate (R13/R16-verified).
// ---------------------------------------------------------------------------
__global__ __launch_bounds__(1024, 4) void k_fused(const float* __restrict__ imgs,
                                                   const unsigned short* __restrict__ Wt4,
                                                   const float* __restrict__ base_g,
                                                   const float* __restrict__ W_f,
                                                   float* __restrict__ out) {
    __shared__ __align__(16) float A_s[4][128 * 32];   // 4 x 16 KB fp32
    __shared__ __align__(16) short B_s[2][H_SZ * 32];  // 2 x 32 KB bf16
    __shared__ float att_part[8][128];
    __shared__ float e_s[128];
    __shared__ float scal_r;
    __shared__ float scal_l;

    const int b = blockIdx.x;
    const int t = threadIdx.x;
    const int lane = t & 63, w = t >> 6;
    const int wm = w >> 3, wn = w & 7;           // 2M x 8N wave grid
    const int lr = lane & 15, g = lane >> 4;

    const float* imgb = imgs + (size_t)b * A_RG * DVD;

    // ---- B staging: wave w copies 2KB (2 x 1KB gll) of the 32KB tile ----
    const char* Bg = (const char*)Wt4 + (size_t)w * 2048 + (size_t)lane * 16;
    const unsigned Bld = (unsigned)(w * 2048 + lane * 16);
    // ---- B frag read offsets: frag f = wn*4+n at slab f*1024 + lane*16 ----
    unsigned brd[4];
#pragma unroll
    for (int n = 0; n < 4; ++n)
        brd[n] = (unsigned)((wn * 4 + n) * 1024 + lane * 16);

    // ---- A frag read addrs: row r (128B), chunk (2g+h)^(r&7) ----
    unsigned aLo[4], aHi[4];
#pragma unroll
    for (int mf = 0; mf < 4; ++mf) {
        int r = wm * 64 + mf * 16 + lr;
        aLo[mf] = (unsigned)(r * 128 + (((2 * g)     ^ (r & 7)) << 4));
        aHi[mf] = (unsigned)(r * 128 + (((2 * g + 1) ^ (r & 7)) << 4));
    }

    // ---- A staging: wave w -> rows w*8..w*8+7; lane l -> row w*8+(l>>3),
    //      source chunk (l&7)^(l>>3) (inverse of read swizzle) ----
    const int slr = lane >> 3;
    const int sch = (lane & 7) ^ slr;
    const unsigned Ald = (unsigned)(w * 1024 + lane * 16);

    float o0 = 0.f, o1 = 0.f;           // thread owns out cols 2t, 2t+1
    float m_run = -1e30f, l_run = 0.f;  // live in wave 0

    for (int at = 0; at < 2; ++at) {
        const bool last = (at == 1);
        const int m0 = at * 128;

        const char* AgB = (const char*)(imgb
            + (size_t)min(m0 + w * 8 + slr, A_RG - 1) * DVD) + sch * 16;

        f32x4 acc[4][4] = {};

        auto stA = [&](int kt) {
            gll16(AgB + (size_t)kt * 128, (char*)A_s[kt & 3] + Ald);
        };
        auto stB = [&](int kt) {
            const char* s = Bg + (size_t)kt * 32768;
            char* d = (char*)B_s[kt & 1] + Bld;
            gll16(s, d);
            gll16(s + 1024, d + 1024);
        };
        auto compute = [&](int kt) {
            const char* Ac = (const char*)A_s[kt & 3];
            const char* Bc = (const char*)B_s[kt & 1];
            s16x8 aF[4], bq[4];
#pragma unroll
            for (int mf = 0; mf < 4; ++mf) {
                f32x4 lo = *(const f32x4*)(Ac + aLo[mf]);
                f32x4 hi = *(const f32x4*)(Ac + aHi[mf]);
                u32x4 pk;
                pk[0] = cvt2(lo[0], lo[1]);
                pk[1] = cvt2(lo[2], lo[3]);
                pk[2] = cvt2(hi[0], hi[1]);
                pk[3] = cvt2(hi[2], hi[3]);
                aF[mf] = __builtin_bit_cast(s16x8, pk);
            }
#pragma unroll
            for (int n = 0; n < 4; ++n)
                bq[n] = *(const s16x8*)(Bc + brd[n]);
            __builtin_amdgcn_s_setprio(1);
#pragma unroll
            for (int mf = 0; mf < 4; ++mf)
#pragma unroll
                for (int n = 0; n < 4; ++n)
                    acc[mf][n] = __builtin_amdgcn_mfma_f32_16x16x32_bf16(
                        aF[mf], bq[n], acc[mf][n], 0, 0, 0);
            __builtin_amdgcn_s_setprio(0);
        };

        // ---- prologue: B(0), A(0), A(1) staged; drain; barrier ----
        stB(0);
        stA(0);
        stA(1);
        asm volatile("s_waitcnt vmcnt(0)" ::: "memory");
        __builtin_amdgcn_sched_barrier(0);
        __builtin_amdgcn_s_barrier();

        // ---- K loop: counted-vmcnt fences, loads always in flight ----
        for (int kt = 0; kt < NKT; ++kt) {
            if (kt + 1 < NKT) stB(kt + 1);
            if (kt + 2 < NKT) stA(kt + 2);
            __builtin_amdgcn_sched_barrier(0);
            compute(kt);
            __builtin_amdgcn_sched_barrier(0);
            if (kt + 1 < NKT) {
                if (kt + 2 < NKT)
                    asm volatile("s_waitcnt vmcnt(1) lgkmcnt(0)" ::: "memory");
                else
                    asm volatile("s_waitcnt vmcnt(0) lgkmcnt(0)" ::: "memory");
                __builtin_amdgcn_sched_barrier(0);
                __builtin_amdgcn_s_barrier();
            }
        }

        // ---- score epilogue: this wave's 64 cols -> att_part[wn][row] ----
        {
            float wfv[4], bs[4];
#pragma unroll
            for (int n = 0; n < 4; ++n) {
                int col = wn * 64 + n * 16 + lr;
                wfv[n] = W_f[col];
                bs[n] = base_g[(size_t)b * H_SZ + col];
            }
#pragma unroll
            for (int mf = 0; mf < 4; ++mf) {
                float pj[4] = {0.f, 0.f, 0.f, 0.f};
#pragma unroll
                for (int n = 0; n < 4; ++n) {
                    float a0 = fmaxf(acc[mf][n][0] + bs[n], 0.f);
                    float a1 = fmaxf(acc[mf][n][1] + bs[n], 0.f);
                    float a2 = fmaxf(acc[mf][n][2] + bs[n], 0.f);
                    float a3 = fmaxf(acc[mf][n][3] + bs[n], 0.f);
                    pj[0] = fmaf(a0, wfv[n], pj[0]);
                    pj[1] = fmaf(a1, wfv[n], pj[1]);
                    pj[2] = fmaf(a2, wfv[n], pj[2]);
                    pj[3] = fmaf(a3, wfv[n], pj[3]);
                }
#pragma unroll
                for (int j = 0; j < 4; ++j) {
                    float s = pj[j];
                    s += __shfl_xor(s, 1);
                    s += __shfl_xor(s, 2);
                    s += __shfl_xor(s, 4);
                    s += __shfl_xor(s, 8);   // 16 lr-lanes of this row
                    if (lr == 0)
                        att_part[wn][wm * 64 + mf * 16 + g * 4 + j] = s;
                }
            }
        }
        __builtin_amdgcn_s_barrier();

        // ---- wave 0: online-softmax state update ----
        if (w == 0) {
            int gr0 = m0 + lane, gr1 = m0 + lane + 64;
            float s0, s1;
            {
                float a = 0.f, c = 0.f;
#pragma unroll
                for (int q = 0; q < 8; ++q) {
                    a += att_part[q][lane];
                    c += att_part[q][lane + 64];
                }
                s0 = (gr0 < A_RG) ? a : -1e30f;
                s1 = (gr1 < A_RG) ? c : -1e30f;
            }
            float mx = fmaxf(s0, s1);
            for (int d = 1; d < 64; d <<= 1) mx = fmaxf(mx, __shfl_xor(mx, d));
            float m_new = fmaxf(m_run, mx);
            float r = __expf(m_run - m_new);
            float e0 = __expf(s0 - m_new);
            float e1 = __expf(s1 - m_new);
            float es = e0 + e1;
            for (int d = 1; d < 64; d <<= 1) es += __shfl_xor(es, d);
            l_run = l_run * r + es;
            m_run = m_new;
            e_s[lane] = e0;
            e_s[lane + 64] = e1;
            if (lane == 0) {
                scal_r = r;
                if (last) scal_l = l_run;
            }
        }
        __builtin_amdgcn_s_barrier();

        // ---- V phase: o = o*r + sum_a e[a] * imgs[b, m0+a, 2t..2t+1] ----
        {
            float r = scal_r;
            o0 *= r; o1 *= r;
            const float2* vb = (const float2*)imgb + t;
            const int AV = last ? (A_RG - 128) : 128;   // 68 or 128
#pragma unroll 4
            for (int a = 0; a < AV; ++a) {
                float e = e_s[a];
                float2 v = vb[(size_t)(m0 + a) * (DVD / 2)];
                o0 = fmaf(e, v.x, o0);
                o1 = fmaf(e, v.y, o1);
            }
        }
        // cross-tile LDS hazards covered by the next tile's prologue fence
        // (R13/R16-verified pattern).
    }

    // ---- finalize: out[b, 2t..2t+1] = o / l ----
    float linv = 1.0f / scal_l;
    float2 res = make_float2(o0 * linv, o1 * linv);
    ((float2*)(out + (size_t)b * DVD))[t] = res;
}

// ---------------------------------------------------------------------------
extern "C" void kernel_launch(void* const* d_in, const int* in_sizes, int n_in,
                              void* d_out, int out_size, void* d_ws, size_t ws_size,
                              hipStream_t stream) {
    const float* h_att   = (const float*)d_in[0];
    const float* prev_h2 = (const float*)d_in[1];
    const float* imgs    = (const float*)d_in[2];
    const float* W_v     = (const float*)d_in[3];
    const float* b_v     = (const float*)d_in[4];
    const float* W_ha    = (const float*)d_in[5];
    const float* b_ha    = (const float*)d_in[6];
    const float* W_hv    = (const float*)d_in[7];
    const float* b_hv    = (const float*)d_in[8];
    const float* W_f     = (const float*)d_in[9];
    // d_in[10] = b_f: softmax-invariant additive constant -> unused

    // ws layout: [0,2MB) Wt4 bf16 fragment-packed; [2MB,+512KB) base fp32
    unsigned short* Wt4 = (unsigned short*)d_ws;
    float* base_g = (float*)((char*)d_ws + (size_t)DVD * H_SZ * 2);
    float* out = (float*)d_out;

    hipLaunchKernelGGL(k_prepW, dim3(256), dim3(256), 0, stream, W_v, Wt4);
    hipLaunchKernelGGL(k_base, dim3(256), dim3(256), 0, stream,
                       h_att, prev_h2, W_ha, b_ha, W_hv, b_hv, b_v, base_g);
    hipLaunchKernelGGL(k_fused, dim3(B_SZ), dim3(1024), 0, stream,
                       imgs, Wt4, base_g, W_f, out);
}